// Round 1
// baseline (1955.421 us; speedup 1.0000x reference)
//
#include <hip/hip_runtime.h>
#include <hip/hip_bf16.h>
#include <math.h>

#define D_IN 256
#define D_OUT 128

// ---------------------------------------------------------------- degree
__global__ void init_deg_k(float* __restrict__ deg, int N) {
    int n = blockIdx.x * blockDim.x + threadIdx.x;
    if (n < N) deg[n] = 1.0f;   // self-loop weight 1
}

__global__ void deg_acc_k(const int* __restrict__ dst, const float* __restrict__ w,
                          float* __restrict__ deg, int E) {
    int e = blockIdx.x * blockDim.x + threadIdx.x;
    if (e < E) atomicAdd(&deg[dst[e]], w[e]);
}

__global__ void rsqrt_k(float* __restrict__ deg, int N) {
    int n = blockIdx.x * blockDim.x + threadIdx.x;
    if (n < N) deg[n] = rsqrtf(deg[n]);   // deg >= 1 always (self-loop)
}

// ---------------------------------------------------------------- GEMM
// H[M,128] = X[M,256] @ W[256,128], fp32.  BM=64, BN=128, BK=16, 256 thr,
// each thread computes 8 rows x 4 cols.
__global__ __launch_bounds__(256) void gemm_k(const float* __restrict__ X,
                                              const float* __restrict__ W,
                                              float* __restrict__ H, int M) {
    __shared__ float As[64][16];
    __shared__ float Bs[16][128];
    const int block_row = blockIdx.x * 64;
    const int tid = threadIdx.x;
    const int tr = tid >> 5;          // 0..7  (row group)
    const int tc = tid & 31;          // 0..31 (col group)

    float acc[8][4];
    #pragma unroll
    for (int i = 0; i < 8; ++i)
        #pragma unroll
        for (int j = 0; j < 4; ++j) acc[i][j] = 0.f;

    for (int k0 = 0; k0 < D_IN; k0 += 16) {
        // stage A: 64x16, float4 per thread, fully coalesced LDS write
        {
            int r  = tid >> 2;            // 0..63
            int kc = (tid & 3) * 4;       // 0,4,8,12
            int gr = block_row + r;
            float4 v = make_float4(0.f, 0.f, 0.f, 0.f);
            if (gr < M) v = *(const float4*)&X[gr * D_IN + k0 + kc];
            *(float4*)&As[r][kc] = v;
        }
        // stage B: 16x128, two float4 per thread
        {
            int r  = tid >> 4;            // 0..15
            int cc = (tid & 15) * 8;      // 0..120
            const float4* s = (const float4*)&W[(k0 + r) * D_OUT + cc];
            *(float4*)&Bs[r][cc]     = s[0];
            *(float4*)&Bs[r][cc + 4] = s[1];
        }
        __syncthreads();
        #pragma unroll
        for (int kk = 0; kk < 16; ++kk) {
            float4 b = *(const float4*)&Bs[kk][tc * 4];
            float a[8];
            #pragma unroll
            for (int i = 0; i < 8; ++i) a[i] = As[tr * 8 + i][kk];
            #pragma unroll
            for (int i = 0; i < 8; ++i) {
                acc[i][0] += a[i] * b.x;
                acc[i][1] += a[i] * b.y;
                acc[i][2] += a[i] * b.z;
                acc[i][3] += a[i] * b.w;
            }
        }
        __syncthreads();
    }
    #pragma unroll
    for (int i = 0; i < 8; ++i) {
        int gr = block_row + tr * 8 + i;
        if (gr < M) {
            float4 v = make_float4(acc[i][0], acc[i][1], acc[i][2], acc[i][3]);
            *(float4*)&H[gr * D_OUT + tc * 4] = v;
        }
    }
}

// ---------------------------------------------------------------- scatter
// One edge per 64-lane wave; each lane handles 2 of the 128 dims (float2).
__global__ __launch_bounds__(256) void scatter_k(const int* __restrict__ src,
                                                 const int* __restrict__ dst,
                                                 const float* __restrict__ w,
                                                 const float* __restrict__ dis,
                                                 const float* __restrict__ h,
                                                 float* __restrict__ agg, int E) {
    int gid = blockIdx.x * blockDim.x + threadIdx.x;
    int e = gid >> 6;
    if (e >= E) return;
    int lane = threadIdx.x & 63;
    int s = src[e];
    int d = dst[e];
    float norm = dis[s] * w[e] * dis[d];
    float2 hv = *(const float2*)&h[s * D_OUT + lane * 2];
    atomicAdd(&agg[d * D_OUT + lane * 2],     hv.x * norm);
    atomicAdd(&agg[d * D_OUT + lane * 2 + 1], hv.y * norm);
}

// ---------------------------------------------------------------- finish
// val = relu(agg + dis^2 * h + b);  pooled[batch[n]] += val  (batch sorted ->
// register accumulate per segment, flush on graph change).
__global__ __launch_bounds__(256) void finish_k(const float* __restrict__ agg,
                                                const float* __restrict__ h,
                                                const float* __restrict__ dis,
                                                const float* __restrict__ bconv,
                                                const int* __restrict__ batch,
                                                float* __restrict__ pooled, int N) {
    int n0 = blockIdx.x * 64;          // 64 nodes per block
    int t = threadIdx.x;
    int c = t & 127;
    int par = t >> 7;                  // 0 or 1
    float b = bconv[c];
    float accv = 0.f;
    int curg = -1;
    #pragma unroll 1
    for (int i = 0; i < 32; ++i) {
        int n = n0 + par + 2 * i;
        if (n >= N) break;
        int g = batch[n];
        float di = dis[n];
        int idx = n * D_OUT + c;
        float v = fmaxf(agg[idx] + di * di * h[idx] + b, 0.f);
        if (g != curg) {
            if (curg >= 0) atomicAdd(&pooled[curg * D_OUT + c], accv);
            accv = 0.f;
            curg = g;
        }
        accv += v;
    }
    if (curg >= 0) atomicAdd(&pooled[curg * D_OUT + c], accv);
}

__global__ void count_k(const int* __restrict__ batch, float* __restrict__ counts, int N) {
    int n = blockIdx.x * blockDim.x + threadIdx.x;
    if (n < N) atomicAdd(&counts[batch[n]], 1.0f);
}

// ---------------------------------------------------------------- head
// out[g] = sigmoid( (pooled[g] . W_lin) / max(count,1) + b_lin )
__global__ void head_k(const float* __restrict__ pooled, const float* __restrict__ counts,
                       const float* __restrict__ wlin, const float* __restrict__ blin,
                       float* __restrict__ out, int G) {
    int g = blockIdx.x;
    int lane = threadIdx.x;            // 64 threads
    float s = 0.f;
    for (int c = lane; c < D_OUT; c += 64)
        s += pooled[g * D_OUT + c] * wlin[c];
    #pragma unroll
    for (int off = 32; off; off >>= 1) s += __shfl_down(s, off);
    if (lane == 0) {
        float cnt = fmaxf(counts[g], 1.0f);
        float z = s / cnt + blin[0];
        out[g] = 1.0f / (1.0f + expf(-z));
    }
}

// ---------------------------------------------------------------- launcher
extern "C" void kernel_launch(void* const* d_in, const int* in_sizes, int n_in,
                              void* d_out, int out_size, void* d_ws, size_t ws_size,
                              hipStream_t stream) {
    const float* x     = (const float*)d_in[0];
    const int*   ei    = (const int*)  d_in[1];   // [2,E] -> src then dst
    const float* ew    = (const float*)d_in[2];
    const int*   batch = (const int*)  d_in[3];
    const float* Wc    = (const float*)d_in[4];
    const float* bc    = (const float*)d_in[5];
    const float* Wl    = (const float*)d_in[6];
    const float* bl    = (const float*)d_in[7];
    float* out = (float*)d_out;

    const int E = in_sizes[2];
    const int N = in_sizes[3];
    const int G = out_size;

    const int* src = ei;
    const int* dst = ei + E;

    float* ws     = (float*)d_ws;
    float* deg    = ws;                               // N
    float* h      = deg + N;                          // N*128
    float* agg    = h + (size_t)N * D_OUT;            // N*128
    float* pooled = agg + (size_t)N * D_OUT;          // G*128
    float* counts = pooled + (size_t)G * D_OUT;       // G

    // zero agg + pooled + counts (contiguous region) every call
    size_t zbytes = ((size_t)N * D_OUT + (size_t)G * D_OUT + G) * sizeof(float);
    hipMemsetAsync(agg, 0, zbytes, stream);

    init_deg_k<<<(N + 255) / 256, 256, 0, stream>>>(deg, N);
    deg_acc_k <<<(E + 255) / 256, 256, 0, stream>>>(dst, ew, deg, E);
    rsqrt_k   <<<(N + 255) / 256, 256, 0, stream>>>(deg, N);
    gemm_k    <<<(N + 63) / 64, 256, 0, stream>>>(x, Wc, h, N);
    {
        long long threads = (long long)E * 64;
        int blocks = (int)((threads + 255) / 256);
        scatter_k<<<blocks, 256, 0, stream>>>(src, dst, ew, deg, h, agg, E);
    }
    finish_k  <<<(N + 63) / 64, 256, 0, stream>>>(agg, h, deg, bc, batch, pooled, N);
    count_k   <<<(N + 255) / 256, 256, 0, stream>>>(batch, counts, N);
    head_k    <<<G, 64, 0, stream>>>(pooled, counts, Wl, bl, out, G);
}

// Round 2
// 492.787 us; speedup vs baseline: 3.9681x; 3.9681x over previous
//
#include <hip/hip_runtime.h>
#include <hip/hip_bf16.h>
#include <math.h>

#define D_IN 256
#define D_OUT 128

// ---------------------------------------------------------------- degree + indegree
__global__ void init_deg_k(float* __restrict__ deg, int N) {
    int n = blockIdx.x * blockDim.x + threadIdx.x;
    if (n < N) deg[n] = 1.0f;   // self-loop weight 1
}

__global__ void deg_k(const int* __restrict__ dst, const float* __restrict__ w,
                      float* __restrict__ deg, int* __restrict__ cnt, int E) {
    int e = blockIdx.x * blockDim.x + threadIdx.x;
    if (e < E) {
        int d = dst[e];
        atomicAdd(&deg[d], w[e]);
        atomicAdd(&cnt[d], 1);
    }
}

__global__ void rsqrt_k(float* __restrict__ deg, int N) {
    int n = blockIdx.x * blockDim.x + threadIdx.x;
    if (n < N) deg[n] = rsqrtf(deg[n]);   // deg >= 1 always (self-loop)
}

// ---------------------------------------------------------------- scan (exclusive, 1024/block)
__global__ __launch_bounds__(256) void scan1_k(const int* __restrict__ cnt,
                                               int* __restrict__ row_start,
                                               int* __restrict__ blksum, int N) {
    __shared__ int sdata[256];
    int t = threadIdx.x;
    int base = blockIdx.x * 1024;
    int v[4], s = 0;
    #pragma unroll
    for (int i = 0; i < 4; ++i) {
        int idx = base + t * 4 + i;
        v[i] = (idx < N) ? cnt[idx] : 0;
        s += v[i];
    }
    sdata[t] = s;
    __syncthreads();
    // Hillis-Steele inclusive scan over 256 thread sums
    #pragma unroll
    for (int off = 1; off < 256; off <<= 1) {
        int x = 0;
        if (t >= off) x = sdata[t - off];
        __syncthreads();
        sdata[t] += x;
        __syncthreads();
    }
    int excl = sdata[t] - s;
    if (t == 255) blksum[blockIdx.x] = sdata[t];
    int run = excl;
    #pragma unroll
    for (int i = 0; i < 4; ++i) {
        int idx = base + t * 4 + i;
        if (idx < N) row_start[idx] = run;
        run += v[i];
    }
}

__global__ void scan2_k(const int* __restrict__ blksum, int* __restrict__ blkpre,
                        int NB, int* __restrict__ row_start, int N) {
    if (threadIdx.x == 0 && blockIdx.x == 0) {
        int run = 0;
        for (int i = 0; i < NB; ++i) { blkpre[i] = run; run += blksum[i]; }
        row_start[N] = run;   // == E
    }
}

__global__ void scan3_k(int* __restrict__ row_start, const int* __restrict__ blkpre, int N) {
    int idx = blockIdx.x * blockDim.x + threadIdx.x;
    if (idx < N) row_start[idx] += blkpre[idx >> 10];
}

// ---------------------------------------------------------------- CSR fill
__global__ void fill_k(const int* __restrict__ src, const int* __restrict__ dst,
                       const float* __restrict__ w, const float* __restrict__ dis,
                       const int* __restrict__ row_start, int* __restrict__ cursor,
                       int2* __restrict__ csr, int E) {
    int e = blockIdx.x * blockDim.x + threadIdx.x;
    if (e >= E) return;
    int s = src[e];
    int d = dst[e];
    int pos = atomicAdd(&cursor[d], 1);
    float nm = dis[s] * w[e] * dis[d];
    int2 rec;
    rec.x = s;
    rec.y = __float_as_int(nm);
    csr[row_start[d] + pos] = rec;
}

// ---------------------------------------------------------------- GEMM
// H[M,128] = X[M,256] @ W[256,128], fp32.  BM=64, BN=128, BK=16, 256 thr.
__global__ __launch_bounds__(256) void gemm_k(const float* __restrict__ X,
                                              const float* __restrict__ W,
                                              float* __restrict__ H, int M) {
    __shared__ float As[64][16];
    __shared__ float Bs[16][128];
    const int block_row = blockIdx.x * 64;
    const int tid = threadIdx.x;
    const int tr = tid >> 5;
    const int tc = tid & 31;

    float acc[8][4];
    #pragma unroll
    for (int i = 0; i < 8; ++i)
        #pragma unroll
        for (int j = 0; j < 4; ++j) acc[i][j] = 0.f;

    for (int k0 = 0; k0 < D_IN; k0 += 16) {
        {
            int r  = tid >> 2;
            int kc = (tid & 3) * 4;
            int gr = block_row + r;
            float4 v = make_float4(0.f, 0.f, 0.f, 0.f);
            if (gr < M) v = *(const float4*)&X[gr * D_IN + k0 + kc];
            *(float4*)&As[r][kc] = v;
        }
        {
            int r  = tid >> 4;
            int cc = (tid & 15) * 8;
            const float4* s = (const float4*)&W[(k0 + r) * D_OUT + cc];
            *(float4*)&Bs[r][cc]     = s[0];
            *(float4*)&Bs[r][cc + 4] = s[1];
        }
        __syncthreads();
        #pragma unroll
        for (int kk = 0; kk < 16; ++kk) {
            float4 b = *(const float4*)&Bs[kk][tc * 4];
            float a[8];
            #pragma unroll
            for (int i = 0; i < 8; ++i) a[i] = As[tr * 8 + i][kk];
            #pragma unroll
            for (int i = 0; i < 8; ++i) {
                acc[i][0] += a[i] * b.x;
                acc[i][1] += a[i] * b.y;
                acc[i][2] += a[i] * b.z;
                acc[i][3] += a[i] * b.w;
            }
        }
        __syncthreads();
    }
    #pragma unroll
    for (int i = 0; i < 8; ++i) {
        int gr = block_row + tr * 8 + i;
        if (gr < M) {
            float4 v = make_float4(acc[i][0], acc[i][1], acc[i][2], acc[i][3]);
            *(float4*)&H[gr * D_OUT + tc * 4] = v;
        }
    }
}

// ---------------------------------------------------------------- aggregate + relu + pool
// One wave per node (4 waves/block, 16 nodes per wave, stride 4).
// lane handles dims [2*lane, 2*lane+1]. Self-loop analytic. Pool into
// pooled[batch[n]] with register run-accumulation (batch sorted).
__global__ __launch_bounds__(256) void agg_pool_k(const int* __restrict__ row_start,
                                                  const int2* __restrict__ csr,
                                                  const float* __restrict__ h,
                                                  const float* __restrict__ dis,
                                                  const float* __restrict__ bconv,
                                                  const int* __restrict__ batch,
                                                  float* __restrict__ pooled,
                                                  float* __restrict__ counts, int N) {
    int wave = threadIdx.x >> 6;        // 0..3
    int lane = threadIdx.x & 63;
    int c = lane * 2;
    float2 b2 = *(const float2*)&bconv[c];
    int base = blockIdx.x * 64 + wave;  // node = base + 4*i

    float2 accp = make_float2(0.f, 0.f);
    int curg = -1;
    float gcount = 0.f;

    #pragma unroll 1
    for (int i = 0; i < 16; ++i) {
        int n = base + 4 * i;
        if (n >= N) break;
        int rs = row_start[n];
        int re = row_start[n + 1];
        float din = dis[n];
        float2 hn = *(const float2*)&h[(size_t)n * D_OUT + c];
        float ax = din * din * hn.x;
        float ay = din * din * hn.y;
        int j = rs;
        // 2x unrolled gather loop (two outstanding loads)
        for (; j + 1 < re; j += 2) {
            int2 r0 = csr[j];
            int2 r1 = csr[j + 1];
            float nm0 = __int_as_float(r0.y);
            float nm1 = __int_as_float(r1.y);
            float2 h0 = *(const float2*)&h[(size_t)r0.x * D_OUT + c];
            float2 h1 = *(const float2*)&h[(size_t)r1.x * D_OUT + c];
            ax += nm0 * h0.x + nm1 * h1.x;
            ay += nm0 * h0.y + nm1 * h1.y;
        }
        if (j < re) {
            int2 r0 = csr[j];
            float nm0 = __int_as_float(r0.y);
            float2 h0 = *(const float2*)&h[(size_t)r0.x * D_OUT + c];
            ax += nm0 * h0.x;
            ay += nm0 * h0.y;
        }
        float vx = fmaxf(ax + b2.x, 0.f);
        float vy = fmaxf(ay + b2.y, 0.f);
        int g = batch[n];
        if (g != curg) {
            if (curg >= 0) {
                atomicAdd(&pooled[curg * D_OUT + c],     accp.x);
                atomicAdd(&pooled[curg * D_OUT + c + 1], accp.y);
                if (lane == 0) atomicAdd(&counts[curg], gcount);
            }
            accp = make_float2(0.f, 0.f);
            gcount = 0.f;
            curg = g;
        }
        accp.x += vx;
        accp.y += vy;
        gcount += 1.f;
    }
    if (curg >= 0) {
        atomicAdd(&pooled[curg * D_OUT + c],     accp.x);
        atomicAdd(&pooled[curg * D_OUT + c + 1], accp.y);
        if (lane == 0) atomicAdd(&counts[curg], gcount);
    }
}

// ---------------------------------------------------------------- head
__global__ void head_k(const float* __restrict__ pooled, const float* __restrict__ counts,
                       const float* __restrict__ wlin, const float* __restrict__ blin,
                       float* __restrict__ out, int G) {
    int g = blockIdx.x;
    int lane = threadIdx.x;            // 64 threads
    float s = 0.f;
    for (int c = lane; c < D_OUT; c += 64)
        s += pooled[g * D_OUT + c] * wlin[c];
    #pragma unroll
    for (int off = 32; off; off >>= 1) s += __shfl_down(s, off);
    if (lane == 0) {
        float cnt = fmaxf(counts[g], 1.0f);
        float z = s / cnt + blin[0];
        out[g] = 1.0f / (1.0f + expf(-z));
    }
}

// ---------------------------------------------------------------- launcher
extern "C" void kernel_launch(void* const* d_in, const int* in_sizes, int n_in,
                              void* d_out, int out_size, void* d_ws, size_t ws_size,
                              hipStream_t stream) {
    const float* x     = (const float*)d_in[0];
    const int*   ei    = (const int*)  d_in[1];   // [2,E] -> src then dst
    const float* ew    = (const float*)d_in[2];
    const int*   batch = (const int*)  d_in[3];
    const float* Wc    = (const float*)d_in[4];
    const float* bc    = (const float*)d_in[5];
    const float* Wl    = (const float*)d_in[6];
    const float* bl    = (const float*)d_in[7];
    float* out = (float*)d_out;

    const int E = in_sizes[2];
    const int N = in_sizes[3];
    const int G = out_size;
    const int NB = (N + 1023) >> 10;   // scan blocks

    const int* src = ei;
    const int* dst = ei + E;

    // ---- workspace layout
    float* deg      = (float*)d_ws;                    // N
    float* h        = deg + N;                         // N*128
    int2*  csr      = (int2*)(h + (size_t)N * D_OUT);  // E   (8B-aligned: (N+N*128)*4 % 8 == 0)
    int*   row_start= (int*)(csr + E);                 // N+1
    int*   blksum   = row_start + N + 1;               // NB
    int*   blkpre   = blksum + NB;                     // NB
    // ---- zeroed-every-call region (contiguous)
    float* pooled   = (float*)(blkpre + NB);           // G*128
    float* counts   = pooled + (size_t)G * D_OUT;      // G
    int*   cnt      = (int*)(counts + G);              // N
    int*   cursor   = cnt + N;                         // N

    size_t zbytes = ((size_t)G * D_OUT + G + 2 * (size_t)N) * sizeof(int);
    hipMemsetAsync(pooled, 0, zbytes, stream);

    init_deg_k<<<(N + 255) / 256, 256, 0, stream>>>(deg, N);
    deg_k     <<<(E + 255) / 256, 256, 0, stream>>>(dst, ew, deg, cnt, E);
    rsqrt_k   <<<(N + 255) / 256, 256, 0, stream>>>(deg, N);

    gemm_k    <<<(N + 63) / 64, 256, 0, stream>>>(x, Wc, h, N);

    scan1_k   <<<NB, 256, 0, stream>>>(cnt, row_start, blksum, N);
    scan2_k   <<<1, 64, 0, stream>>>(blksum, blkpre, NB, row_start, N);
    scan3_k   <<<(N + 255) / 256, 256, 0, stream>>>(row_start, blkpre, N);

    fill_k    <<<(E + 255) / 256, 256, 0, stream>>>(src, dst, ew, deg, row_start, cursor, csr, E);

    agg_pool_k<<<(N + 63) / 64, 256, 0, stream>>>(row_start, csr, h, deg, bc, batch, pooled, counts, N);

    head_k    <<<G, 64, 0, stream>>>(pooled, counts, Wl, bl, out, G);
}

// Round 3
// 379.885 us; speedup vs baseline: 5.1474x; 1.2972x over previous
//
#include <hip/hip_runtime.h>
#include <hip/hip_bf16.h>
#include <math.h>

#define D_IN 256
#define D_OUT 128

typedef __bf16 bf16x8 __attribute__((ext_vector_type(8)));
typedef float  f32x4  __attribute__((ext_vector_type(4)));

__device__ __forceinline__ float b2f(ushort u) {
    union { unsigned int i; float f; } v; v.i = ((unsigned int)u) << 16; return v.f;
}
__device__ __forceinline__ ushort f2b(float f) {   // RNE
    unsigned int x = __float_as_uint(f);
    unsigned int r = (x + 0x7FFFu + ((x >> 16) & 1u)) >> 16;
    return (ushort)r;
}

// ---------------------------------------------------------------- degree + indegree
__global__ void init_deg_k(float* __restrict__ deg, int N) {
    int n = blockIdx.x * blockDim.x + threadIdx.x;
    if (n < N) deg[n] = 1.0f;   // self-loop weight 1
}

__global__ void deg_k(const int* __restrict__ dst, const float* __restrict__ w,
                      float* __restrict__ deg, int* __restrict__ cnt, int E) {
    int e = blockIdx.x * blockDim.x + threadIdx.x;
    if (e < E) {
        int d = dst[e];
        atomicAdd(&deg[d], w[e]);
        atomicAdd(&cnt[d], 1);
    }
}

__global__ void rsqrt_k(float* __restrict__ deg, int N) {
    int n = blockIdx.x * blockDim.x + threadIdx.x;
    if (n < N) deg[n] = rsqrtf(deg[n]);   // deg >= 1 always
}

// ---------------------------------------------------------------- scan (exclusive)
__global__ __launch_bounds__(256) void scan1_k(const int* __restrict__ cnt,
                                               int* __restrict__ row_start,
                                               int* __restrict__ blksum, int N) {
    __shared__ int sdata[256];
    int t = threadIdx.x;
    int base = blockIdx.x * 1024;
    int v[4], s = 0;
    #pragma unroll
    for (int i = 0; i < 4; ++i) {
        int idx = base + t * 4 + i;
        v[i] = (idx < N) ? cnt[idx] : 0;
        s += v[i];
    }
    sdata[t] = s;
    __syncthreads();
    #pragma unroll
    for (int off = 1; off < 256; off <<= 1) {
        int x = 0;
        if (t >= off) x = sdata[t - off];
        __syncthreads();
        sdata[t] += x;
        __syncthreads();
    }
    int excl = sdata[t] - s;
    if (t == 255) blksum[blockIdx.x] = sdata[t];
    int run = excl;
    #pragma unroll
    for (int i = 0; i < 4; ++i) {
        int idx = base + t * 4 + i;
        if (idx < N) row_start[idx] = run;
        run += v[i];
    }
}

// parallel block-sum scan (NB <= 256)
__global__ __launch_bounds__(256) void scan2_k(const int* __restrict__ blksum,
                                               int* __restrict__ blkpre,
                                               int NB, int* __restrict__ row_start, int N) {
    __shared__ int s[256];
    int t = threadIdx.x;
    int v = (t < NB) ? blksum[t] : 0;
    s[t] = v;
    __syncthreads();
    #pragma unroll
    for (int off = 1; off < 256; off <<= 1) {
        int x = 0;
        if (t >= off) x = s[t - off];
        __syncthreads();
        s[t] += x;
        __syncthreads();
    }
    if (t < NB) blkpre[t] = s[t] - v;
    if (t == 255) row_start[N] = s[255];
}

__global__ void scan3_k(int* __restrict__ row_start, const int* __restrict__ blkpre, int N) {
    int idx = blockIdx.x * blockDim.x + threadIdx.x;
    if (idx < N) row_start[idx] += blkpre[idx >> 10];
}

// ---------------------------------------------------------------- CSR fill
__global__ void fill_k(const int* __restrict__ src, const int* __restrict__ dst,
                       const float* __restrict__ w, const float* __restrict__ dis,
                       const int* __restrict__ row_start, int* __restrict__ cursor,
                       int2* __restrict__ csr, int E) {
    int e = blockIdx.x * blockDim.x + threadIdx.x;
    if (e >= E) return;
    int s = src[e];
    int d = dst[e];
    int pos = atomicAdd(&cursor[d], 1);
    float nm = dis[s] * w[e] * dis[d];
    int2 rec;
    rec.x = s;
    rec.y = __float_as_int(nm);
    csr[row_start[d] + pos] = rec;
}

// ---------------------------------------------------------------- W^T precompute (fp32 -> bf16)
__global__ void wt_k(const float* __restrict__ W, ushort* __restrict__ Wtg) {
    int t = blockIdx.x * 256 + threadIdx.x;   // 256*128 = 32768
    if (t < D_IN * D_OUT) {
        int k = t >> 7, n = t & 127;
        Wtg[n * D_IN + k] = f2b(W[t]);
    }
}

// ---------------------------------------------------------------- MFMA GEMM
// H[M,128](bf16) = X[M,256](fp32->bf16) @ W(via Wtg bf16 [128 cols][256 k]).
// BM=128 rows/block, 4 waves; each wave: all 128 rows x 32 cols (wid*32).
// B-frags preloaded to regs (16 frags); x staged to 64KB XOR-swizzled LDS.
__global__ __launch_bounds__(256, 2) void gemm_k(const float* __restrict__ X,
                                                 const ushort* __restrict__ Wtg,
                                                 ushort* __restrict__ H, int M) {
    extern __shared__ char smem[];            // 65536 B = xs[128 rows][256 bf16]
    const int t = threadIdx.x;
    const int brow = blockIdx.x * 128;
    const int wid = t >> 6;
    const int lane = t & 63;
    const int lrow = lane & 15;
    const int lkc = lane >> 4;                // 0..3

    // ---- preload B fragments: cols wid*32 + n*16 + lrow, k = kk*32 + lkc*8
    bf16x8 breg[2][8];
    #pragma unroll
    for (int n = 0; n < 2; ++n) {
        int col = wid * 32 + n * 16 + lrow;
        const char* base = (const char*)(Wtg + col * D_IN);
        #pragma unroll
        for (int kk = 0; kk < 8; ++kk)
            breg[n][kk] = *(const bf16x8*)(base + kk * 64 + lkc * 16);
    }

    // ---- stage x tile: 128 rows x 256 fp32 -> bf16 LDS (16B-chunk XOR swizzle)
    {
        const float4* x4 = (const float4*)X;
        #pragma unroll
        for (int i = 0; i < 32; ++i) {
            int f = t + 256 * i;              // 8192 float4s
            int row = f >> 6;
            int c4 = f & 63;
            int gr = brow + row;
            if (gr > M - 1) gr = M - 1;       // clamp (masked at epilogue)
            float4 v = x4[(size_t)gr * 64 + c4];
            ushort4 u;
            u.x = f2b(v.x); u.y = f2b(v.y); u.z = f2b(v.z); u.w = f2b(v.w);
            int phys = row * 512 + (((c4 >> 1) ^ (row & 7)) << 4) + ((c4 & 1) << 3);
            *(ushort4*)(smem + phys) = u;
        }
    }
    __syncthreads();

    // ---- MFMA main loop
    f32x4 acc[8][2];
    #pragma unroll
    for (int m = 0; m < 8; ++m)
        #pragma unroll
        for (int n = 0; n < 2; ++n) acc[m][n] = (f32x4){0.f, 0.f, 0.f, 0.f};

    #pragma unroll
    for (int kk = 0; kk < 8; ++kk) {
        bf16x8 a[8];
        #pragma unroll
        for (int m = 0; m < 8; ++m) {
            int row = m * 16 + lrow;
            int chunk = kk * 4 + lkc;
            a[m] = *(const bf16x8*)(smem + row * 512 + ((chunk ^ (row & 7)) << 4));
        }
        #pragma unroll
        for (int m = 0; m < 8; ++m) {
            acc[m][0] = __builtin_amdgcn_mfma_f32_16x16x32_bf16(a[m], breg[0][kk], acc[m][0], 0, 0, 0);
            acc[m][1] = __builtin_amdgcn_mfma_f32_16x16x32_bf16(a[m], breg[1][kk], acc[m][1], 0, 0, 0);
        }
    }

    // ---- epilogue: C/D layout col=lane&15, row=(lane>>4)*4+v
    #pragma unroll
    for (int m = 0; m < 8; ++m) {
        #pragma unroll
        for (int v = 0; v < 4; ++v) {
            int gr = brow + m * 16 + lkc * 4 + v;
            if (gr < M) {
                size_t rb = (size_t)gr * D_OUT;
                H[rb + wid * 32 + lrow]      = f2b(acc[m][0][v]);
                H[rb + wid * 32 + 16 + lrow] = f2b(acc[m][1][v]);
            }
        }
    }
}

// ---------------------------------------------------------------- aggregate + relu + pool
// One wave per node; lane handles dims [2*lane, 2*lane+1] (bf16 h).
__global__ __launch_bounds__(256) void agg_pool_k(const int* __restrict__ row_start,
                                                  const int2* __restrict__ csr,
                                                  const ushort* __restrict__ h,
                                                  const float* __restrict__ dis,
                                                  const float* __restrict__ bconv,
                                                  const int* __restrict__ batch,
                                                  float* __restrict__ pooled,
                                                  float* __restrict__ counts, int N) {
    int wave = threadIdx.x >> 6;        // 0..3
    int lane = threadIdx.x & 63;
    int c = lane * 2;
    float2 b2 = *(const float2*)&bconv[c];
    int base = blockIdx.x * 64 + wave;

    float2 accp = make_float2(0.f, 0.f);
    int curg = -1;
    float gcount = 0.f;

    #pragma unroll 1
    for (int i = 0; i < 16; ++i) {
        int n = base + 4 * i;
        if (n >= N) break;
        int rs = row_start[n];
        int re = row_start[n + 1];
        float din = dis[n];
        ushort2 hu = *(const ushort2*)&h[(size_t)n * D_OUT + c];
        float ax = din * din * b2f(hu.x);
        float ay = din * din * b2f(hu.y);
        int j = rs;
        for (; j + 3 < re; j += 4) {
            int2 r0 = csr[j];
            int2 r1 = csr[j + 1];
            int2 r2 = csr[j + 2];
            int2 r3 = csr[j + 3];
            ushort2 u0 = *(const ushort2*)&h[(size_t)r0.x * D_OUT + c];
            ushort2 u1 = *(const ushort2*)&h[(size_t)r1.x * D_OUT + c];
            ushort2 u2 = *(const ushort2*)&h[(size_t)r2.x * D_OUT + c];
            ushort2 u3 = *(const ushort2*)&h[(size_t)r3.x * D_OUT + c];
            float n0 = __int_as_float(r0.y), n1 = __int_as_float(r1.y);
            float n2 = __int_as_float(r2.y), n3 = __int_as_float(r3.y);
            ax += n0 * b2f(u0.x) + n1 * b2f(u1.x) + n2 * b2f(u2.x) + n3 * b2f(u3.x);
            ay += n0 * b2f(u0.y) + n1 * b2f(u1.y) + n2 * b2f(u2.y) + n3 * b2f(u3.y);
        }
        for (; j < re; ++j) {
            int2 r0 = csr[j];
            ushort2 u0 = *(const ushort2*)&h[(size_t)r0.x * D_OUT + c];
            float n0 = __int_as_float(r0.y);
            ax += n0 * b2f(u0.x);
            ay += n0 * b2f(u0.y);
        }
        float vx = fmaxf(ax + b2.x, 0.f);
        float vy = fmaxf(ay + b2.y, 0.f);
        int g = batch[n];
        if (g != curg) {
            if (curg >= 0) {
                atomicAdd(&pooled[curg * D_OUT + c],     accp.x);
                atomicAdd(&pooled[curg * D_OUT + c + 1], accp.y);
                if (lane == 0) atomicAdd(&counts[curg], gcount);
            }
            accp = make_float2(0.f, 0.f);
            gcount = 0.f;
            curg = g;
        }
        accp.x += vx;
        accp.y += vy;
        gcount += 1.f;
    }
    if (curg >= 0) {
        atomicAdd(&pooled[curg * D_OUT + c],     accp.x);
        atomicAdd(&pooled[curg * D_OUT + c + 1], accp.y);
        if (lane == 0) atomicAdd(&counts[curg], gcount);
    }
}

// ---------------------------------------------------------------- head
__global__ void head_k(const float* __restrict__ pooled, const float* __restrict__ counts,
                       const float* __restrict__ wlin, const float* __restrict__ blin,
                       float* __restrict__ out, int G) {
    int g = blockIdx.x;
    int lane = threadIdx.x;            // 64 threads
    float s = 0.f;
    for (int c = lane; c < D_OUT; c += 64)
        s += pooled[g * D_OUT + c] * wlin[c];
    #pragma unroll
    for (int off = 32; off; off >>= 1) s += __shfl_down(s, off);
    if (lane == 0) {
        float cnt = fmaxf(counts[g], 1.0f);
        float z = s / cnt + blin[0];
        out[g] = 1.0f / (1.0f + expf(-z));
    }
}

// ---------------------------------------------------------------- launcher
extern "C" void kernel_launch(void* const* d_in, const int* in_sizes, int n_in,
                              void* d_out, int out_size, void* d_ws, size_t ws_size,
                              hipStream_t stream) {
    const float* x     = (const float*)d_in[0];
    const int*   ei    = (const int*)  d_in[1];   // [2,E] -> src then dst
    const float* ew    = (const float*)d_in[2];
    const int*   batch = (const int*)  d_in[3];
    const float* Wc    = (const float*)d_in[4];
    const float* bc    = (const float*)d_in[5];
    const float* Wl    = (const float*)d_in[6];
    const float* bl    = (const float*)d_in[7];
    float* out = (float*)d_out;

    const int E = in_sizes[2];
    const int N = in_sizes[3];
    const int G = out_size;
    const int NB = (N + 1023) >> 10;

    const int* src = ei;
    const int* dst = ei + E;

    // ---- workspace layout
    float*  deg      = (float*)d_ws;                     // N floats
    ushort* h        = (ushort*)(deg + N);               // N*128 bf16
    ushort* Wtg      = h + (size_t)N * D_OUT;            // 128*256 bf16 (64KB)
    int2*   csr      = (int2*)(Wtg + D_IN * D_OUT);      // E
    int*    row_start= (int*)(csr + E);                  // N+1
    int*    blksum   = row_start + N + 1;                // NB
    int*    blkpre   = blksum + NB;                      // NB
    // ---- zeroed-every-call region (contiguous)
    float*  pooled   = (float*)(blkpre + NB);            // G*128
    float*  counts   = pooled + (size_t)G * D_OUT;       // G
    int*    cnt      = (int*)(counts + G);               // N
    int*    cursor   = cnt + N;                          // N

    size_t zbytes = ((size_t)G * D_OUT + G + 2 * (size_t)N) * sizeof(int);
    hipMemsetAsync(pooled, 0, zbytes, stream);

    init_deg_k<<<(N + 255) / 256, 256, 0, stream>>>(deg, N);
    deg_k     <<<(E + 255) / 256, 256, 0, stream>>>(dst, ew, deg, cnt, E);
    rsqrt_k   <<<(N + 255) / 256, 256, 0, stream>>>(deg, N);

    wt_k      <<<(D_IN * D_OUT + 255) / 256, 256, 0, stream>>>(Wc, Wtg);
    gemm_k    <<<(N + 127) / 128, 256, 65536, stream>>>(x, Wtg, h, N);

    scan1_k   <<<NB, 256, 0, stream>>>(cnt, row_start, blksum, N);
    scan2_k   <<<1, 256, 0, stream>>>(blksum, blkpre, NB, row_start, N);
    scan3_k   <<<(N + 255) / 256, 256, 0, stream>>>(row_start, blkpre, N);

    fill_k    <<<(E + 255) / 256, 256, 0, stream>>>(src, dst, ew, deg, row_start, cursor, csr, E);

    agg_pool_k<<<(N + 63) / 64, 256, 0, stream>>>(row_start, csr, h, deg, bc, batch, pooled, counts, N);

    head_k    <<<G, 64, 0, stream>>>(pooled, counts, Wl, bl, out, G);
}

// Round 4
// 261.788 us; speedup vs baseline: 7.4695x; 1.4511x over previous
//
#include <hip/hip_runtime.h>
#include <hip/hip_bf16.h>
#include <math.h>

#define D_IN 256
#define D_OUT 128
#define WSCALE 1073741824.0f   // 2^30 fixed-point scale for edge weights

typedef __bf16 bf16x8 __attribute__((ext_vector_type(8)));
typedef float  f32x4  __attribute__((ext_vector_type(4)));

__device__ __forceinline__ float b2f(ushort u) {
    union { unsigned int i; float f; } v; v.i = ((unsigned int)u) << 16; return v.f;
}
__device__ __forceinline__ ushort f2b(float f) {   // RNE
    unsigned int x = __float_as_uint(f);
    unsigned int r = (x + 0x7FFFu + ((x >> 16) & 1u)) >> 16;
    return (ushort)r;
}

// ---------------------------------------------------------------- edge pass
// ONE 64-bit atomic per edge: high 24 bits count, low 40 bits fixed-point
// weight sum. Returned old count = this edge's slot within its dst row.
__global__ void edge_k(const int* __restrict__ dst, const float* __restrict__ w,
                       unsigned long long* __restrict__ packed,
                       int* __restrict__ pos, int E) {
    int e = blockIdx.x * blockDim.x + threadIdx.x;
    if (e >= E) return;
    int d = dst[e];
    unsigned long long inc = (1ull << 40) |
        (unsigned long long)(w[e] * WSCALE);
    unsigned long long old = atomicAdd(&packed[d], inc);
    pos[e] = (int)(old >> 40);
}

// ---------------------------------------------------------------- scan (exclusive) + dis
__global__ __launch_bounds__(256) void scan1_k(const unsigned long long* __restrict__ packed,
                                               int* __restrict__ row_start,
                                               int* __restrict__ blksum,
                                               float* __restrict__ dis, int N) {
    __shared__ int sdata[256];
    int t = threadIdx.x;
    int base = blockIdx.x * 1024;
    int v[4], s = 0;
    #pragma unroll
    for (int i = 0; i < 4; ++i) {
        int idx = base + t * 4 + i;
        if (idx < N) {
            unsigned long long p = packed[idx];
            v[i] = (int)(p >> 40);
            float deg = 1.0f + (float)(p & ((1ull << 40) - 1)) * (1.0f / WSCALE);
            dis[idx] = rsqrtf(deg);
        } else v[i] = 0;
        s += v[i];
    }
    sdata[t] = s;
    __syncthreads();
    #pragma unroll
    for (int off = 1; off < 256; off <<= 1) {
        int x = 0;
        if (t >= off) x = sdata[t - off];
        __syncthreads();
        sdata[t] += x;
        __syncthreads();
    }
    int excl = sdata[t] - s;
    if (t == 255) blksum[blockIdx.x] = sdata[t];
    int run = excl;
    #pragma unroll
    for (int i = 0; i < 4; ++i) {
        int idx = base + t * 4 + i;
        if (idx < N) row_start[idx] = run;
        run += v[i];
    }
}

// parallel block-sum scan (NB <= 256)
__global__ __launch_bounds__(256) void scan2_k(const int* __restrict__ blksum,
                                               int* __restrict__ blkpre,
                                               int NB, int* __restrict__ row_start, int N) {
    __shared__ int s[256];
    int t = threadIdx.x;
    int v = (t < NB) ? blksum[t] : 0;
    s[t] = v;
    __syncthreads();
    #pragma unroll
    for (int off = 1; off < 256; off <<= 1) {
        int x = 0;
        if (t >= off) x = s[t - off];
        __syncthreads();
        s[t] += x;
        __syncthreads();
    }
    if (t < NB) blkpre[t] = s[t] - v;
    if (t == 255) row_start[N] = s[255];
}

__global__ void scan3_k(int* __restrict__ row_start, const int* __restrict__ blkpre, int N) {
    int idx = blockIdx.x * blockDim.x + threadIdx.x;
    if (idx < N) row_start[idx] += blkpre[idx >> 10];
}

// ---------------------------------------------------------------- CSR fill (atomic-free)
__global__ void fill_k(const int* __restrict__ src, const int* __restrict__ dst,
                       const float* __restrict__ w, const int* __restrict__ pos,
                       const int* __restrict__ row_start,
                       int2* __restrict__ csr, int E) {
    int e = blockIdx.x * blockDim.x + threadIdx.x;
    if (e >= E) return;
    int d = dst[e];
    int2 rec;
    rec.x = src[e];
    rec.y = __float_as_int(w[e]);
    csr[row_start[d] + pos[e]] = rec;
}

// ---------------------------------------------------------------- W^T precompute (fp32 -> bf16)
__global__ void wt_k(const float* __restrict__ W, ushort* __restrict__ Wtg) {
    int t = blockIdx.x * 256 + threadIdx.x;   // 256*128 = 32768
    if (t < D_IN * D_OUT) {
        int k = t >> 7, n = t & 127;
        Wtg[n * D_IN + k] = f2b(W[t]);
    }
}

// ---------------------------------------------------------------- MFMA GEMM
// H'[M,128](bf16) = dis[row] * (X[M,256] @ W), via Wtg bf16 [128 cols][256 k].
// BM=128 rows/block, 4 waves; each wave: all 128 rows x 32 cols (wid*32).
__global__ __launch_bounds__(256, 2) void gemm_k(const float* __restrict__ X,
                                                 const ushort* __restrict__ Wtg,
                                                 const float* __restrict__ dis,
                                                 ushort* __restrict__ H, int M) {
    extern __shared__ char smem[];            // 65536 B = xs[128 rows][256 bf16]
    const int t = threadIdx.x;
    const int brow = blockIdx.x * 128;
    const int wid = t >> 6;
    const int lane = t & 63;
    const int lrow = lane & 15;
    const int lkc = lane >> 4;                // 0..3

    // ---- preload B fragments: cols wid*32 + n*16 + lrow, k = kk*32 + lkc*8
    bf16x8 breg[2][8];
    #pragma unroll
    for (int n = 0; n < 2; ++n) {
        int col = wid * 32 + n * 16 + lrow;
        const char* base = (const char*)(Wtg + col * D_IN);
        #pragma unroll
        for (int kk = 0; kk < 8; ++kk)
            breg[n][kk] = *(const bf16x8*)(base + kk * 64 + lkc * 16);
    }

    // ---- stage x tile: 128 rows x 256 fp32 -> bf16 LDS (16B-chunk XOR swizzle)
    {
        const float4* x4 = (const float4*)X;
        #pragma unroll
        for (int i = 0; i < 32; ++i) {
            int f = t + 256 * i;              // 8192 float4s
            int row = f >> 6;
            int c4 = f & 63;
            int gr = brow + row;
            if (gr > M - 1) gr = M - 1;       // clamp (masked at epilogue)
            float4 v = x4[(size_t)gr * 64 + c4];
            ushort4 u;
            u.x = f2b(v.x); u.y = f2b(v.y); u.z = f2b(v.z); u.w = f2b(v.w);
            int phys = row * 512 + (((c4 >> 1) ^ (row & 7)) << 4) + ((c4 & 1) << 3);
            *(ushort4*)(smem + phys) = u;
        }
    }
    __syncthreads();

    // ---- MFMA main loop
    f32x4 acc[8][2];
    #pragma unroll
    for (int m = 0; m < 8; ++m)
        #pragma unroll
        for (int n = 0; n < 2; ++n) acc[m][n] = (f32x4){0.f, 0.f, 0.f, 0.f};

    #pragma unroll
    for (int kk = 0; kk < 8; ++kk) {
        bf16x8 a[8];
        #pragma unroll
        for (int m = 0; m < 8; ++m) {
            int row = m * 16 + lrow;
            int chunk = kk * 4 + lkc;
            a[m] = *(const bf16x8*)(smem + row * 512 + ((chunk ^ (row & 7)) << 4));
        }
        #pragma unroll
        for (int m = 0; m < 8; ++m) {
            acc[m][0] = __builtin_amdgcn_mfma_f32_16x16x32_bf16(a[m], breg[0][kk], acc[m][0], 0, 0, 0);
            acc[m][1] = __builtin_amdgcn_mfma_f32_16x16x32_bf16(a[m], breg[1][kk], acc[m][1], 0, 0, 0);
        }
    }

    // ---- epilogue: C/D layout col=lane&15, row=(lane>>4)*4+v; scale by dis[row]
    #pragma unroll
    for (int m = 0; m < 8; ++m) {
        #pragma unroll
        for (int v = 0; v < 4; ++v) {
            int gr = brow + m * 16 + lkc * 4 + v;
            if (gr < M) {
                float dsc = dis[gr];
                size_t rb = (size_t)gr * D_OUT;
                H[rb + wid * 32 + lrow]      = f2b(dsc * acc[m][0][v]);
                H[rb + wid * 32 + 16 + lrow] = f2b(dsc * acc[m][1][v]);
            }
        }
    }
}

// ---------------------------------------------------------------- aggregate + relu + pool
// h is h' = dis[n]*h[n] (bf16). Per node: val = relu(dis[n]*(h'[n] + sum w*h'[src]) + b).
__global__ __launch_bounds__(256) void agg_pool_k(const int* __restrict__ row_start,
                                                  const int2* __restrict__ csr,
                                                  const ushort* __restrict__ h,
                                                  const float* __restrict__ dis,
                                                  const float* __restrict__ bconv,
                                                  const int* __restrict__ batch,
                                                  float* __restrict__ pooled,
                                                  float* __restrict__ counts, int N) {
    int wave = threadIdx.x >> 6;        // 0..3
    int lane = threadIdx.x & 63;
    int c = lane * 2;
    float2 b2 = *(const float2*)&bconv[c];
    int base = blockIdx.x * 64 + wave;

    float2 accp = make_float2(0.f, 0.f);
    int curg = -1;
    float gcount = 0.f;

    #pragma unroll 1
    for (int i = 0; i < 16; ++i) {
        int n = base + 4 * i;
        if (n >= N) break;
        int rs = row_start[n];
        int re = row_start[n + 1];
        float din = dis[n];
        ushort2 hu = *(const ushort2*)&h[(size_t)n * D_OUT + c];
        float ax = b2f(hu.x);            // self-loop: h'[n]
        float ay = b2f(hu.y);
        int j = rs;
        for (; j + 3 < re; j += 4) {
            int2 r0 = csr[j];
            int2 r1 = csr[j + 1];
            int2 r2 = csr[j + 2];
            int2 r3 = csr[j + 3];
            ushort2 u0 = *(const ushort2*)&h[(size_t)r0.x * D_OUT + c];
            ushort2 u1 = *(const ushort2*)&h[(size_t)r1.x * D_OUT + c];
            ushort2 u2 = *(const ushort2*)&h[(size_t)r2.x * D_OUT + c];
            ushort2 u3 = *(const ushort2*)&h[(size_t)r3.x * D_OUT + c];
            float n0 = __int_as_float(r0.y), n1 = __int_as_float(r1.y);
            float n2 = __int_as_float(r2.y), n3 = __int_as_float(r3.y);
            ax += n0 * b2f(u0.x) + n1 * b2f(u1.x) + n2 * b2f(u2.x) + n3 * b2f(u3.x);
            ay += n0 * b2f(u0.y) + n1 * b2f(u1.y) + n2 * b2f(u2.y) + n3 * b2f(u3.y);
        }
        for (; j < re; ++j) {
            int2 r0 = csr[j];
            ushort2 u0 = *(const ushort2*)&h[(size_t)r0.x * D_OUT + c];
            float n0 = __int_as_float(r0.y);
            ax += n0 * b2f(u0.x);
            ay += n0 * b2f(u0.y);
        }
        float vx = fmaxf(din * ax + b2.x, 0.f);
        float vy = fmaxf(din * ay + b2.y, 0.f);
        int g = batch[n];
        if (g != curg) {
            if (curg >= 0) {
                atomicAdd(&pooled[curg * D_OUT + c],     accp.x);
                atomicAdd(&pooled[curg * D_OUT + c + 1], accp.y);
                if (lane == 0) atomicAdd(&counts[curg], gcount);
            }
            accp = make_float2(0.f, 0.f);
            gcount = 0.f;
            curg = g;
        }
        accp.x += vx;
        accp.y += vy;
        gcount += 1.f;
    }
    if (curg >= 0) {
        atomicAdd(&pooled[curg * D_OUT + c],     accp.x);
        atomicAdd(&pooled[curg * D_OUT + c + 1], accp.y);
        if (lane == 0) atomicAdd(&counts[curg], gcount);
    }
}

// ---------------------------------------------------------------- head
__global__ void head_k(const float* __restrict__ pooled, const float* __restrict__ counts,
                       const float* __restrict__ wlin, const float* __restrict__ blin,
                       float* __restrict__ out, int G) {
    int g = blockIdx.x;
    int lane = threadIdx.x;            // 64 threads
    float s = 0.f;
    for (int c = lane; c < D_OUT; c += 64)
        s += pooled[g * D_OUT + c] * wlin[c];
    #pragma unroll
    for (int off = 32; off; off >>= 1) s += __shfl_down(s, off);
    if (lane == 0) {
        float cnt = fmaxf(counts[g], 1.0f);
        float z = s / cnt + blin[0];
        out[g] = 1.0f / (1.0f + expf(-z));
    }
}

// ---------------------------------------------------------------- launcher
extern "C" void kernel_launch(void* const* d_in, const int* in_sizes, int n_in,
                              void* d_out, int out_size, void* d_ws, size_t ws_size,
                              hipStream_t stream) {
    const float* x     = (const float*)d_in[0];
    const int*   ei    = (const int*)  d_in[1];   // [2,E] -> src then dst
    const float* ew    = (const float*)d_in[2];
    const int*   batch = (const int*)  d_in[3];
    const float* Wc    = (const float*)d_in[4];
    const float* bc    = (const float*)d_in[5];
    const float* Wl    = (const float*)d_in[6];
    const float* bl    = (const float*)d_in[7];
    float* out = (float*)d_out;

    const int E = in_sizes[2];
    const int N = in_sizes[3];
    const int G = out_size;
    const int NB = (N + 1023) >> 10;

    const int* src = ei;
    const int* dst = ei + E;

    // ---- workspace layout (zero region first: packed + pooled + counts)
    unsigned long long* packed = (unsigned long long*)d_ws;   // N  (8B aligned)
    float*  pooled   = (float*)(packed + N);                  // G*128
    float*  counts   = pooled + (size_t)G * D_OUT;            // G
    // ---- rest (not zeroed)
    int*    pos      = (int*)(counts + G);                    // E
    float*  dis      = (float*)(pos + E);                     // N
    ushort* h        = (ushort*)(dis + N);                    // N*128 bf16
    ushort* Wtg      = h + (size_t)N * D_OUT;                 // 32768 bf16
    int2*   csr      = (int2*)(Wtg + D_IN * D_OUT);           // E (8B aligned)
    int*    row_start= (int*)(csr + E);                       // N+1
    int*    blksum   = row_start + N + 1;                     // NB
    int*    blkpre   = blksum + NB;                           // NB

    size_t zbytes = (size_t)N * 8 + ((size_t)G * D_OUT + G) * sizeof(float);
    hipMemsetAsync(packed, 0, zbytes, stream);

    edge_k    <<<(E + 255) / 256, 256, 0, stream>>>(dst, ew, packed, pos, E);

    scan1_k   <<<NB, 256, 0, stream>>>(packed, row_start, blksum, dis, N);
    scan2_k   <<<1, 256, 0, stream>>>(blksum, blkpre, NB, row_start, N);
    scan3_k   <<<(N + 255) / 256, 256, 0, stream>>>(row_start, blkpre, N);

    fill_k    <<<(E + 255) / 256, 256, 0, stream>>>(src, dst, ew, pos, row_start, csr, E);

    wt_k      <<<(D_IN * D_OUT + 255) / 256, 256, 0, stream>>>(Wc, Wtg);
    gemm_k    <<<(N + 127) / 128, 256, 65536, stream>>>(x, Wtg, dis, h, N);

    agg_pool_k<<<(N + 63) / 64, 256, 0, stream>>>(row_start, csr, h, dis, bc, batch, pooled, counts, N);

    head_k    <<<G, 64, 0, stream>>>(pooled, counts, Wl, bl, out, G);
}